// Round 5
// baseline (90.085 us; speedup 1.0000x reference)
//
#include <hip/hip_runtime.h>

typedef __attribute__((ext_vector_type(8))) short short8;
typedef __attribute__((ext_vector_type(4))) float f32x4;
typedef __attribute__((ext_vector_type(8))) unsigned short ushort8;

__device__ __forceinline__ unsigned short f2bf(float x) {
  union { float f; unsigned u; } v; v.f = x;
  unsigned r = v.u + 0x7fffu + ((v.u >> 16) & 1u);   // round-to-nearest-even
  return (unsigned short)(r >> 16);
}

// ---------------- W[h][g] -> Wt[g][h] transpose + convert (512x512) ----------
__global__ __launch_bounds__(256) void wt_kernel(
    const float* __restrict__ W, unsigned short* __restrict__ Wt) {
  __shared__ float s[64][65];
  int g0 = blockIdx.x * 64, h0 = blockIdx.y * 64;
  int tx = threadIdx.x & 63, ty = threadIdx.x >> 6;
#pragma unroll
  for (int rr = 0; rr < 16; ++rr) {
    int h = ty * 16 + rr;
    s[h][tx] = W[(long)(h0 + h) * 512 + g0 + tx];
  }
  __syncthreads();
#pragma unroll
  for (int rr = 0; rr < 16; ++rr) {
    int g = ty * 16 + rr;
    Wt[(long)(g0 + g) * 512 + h0 + tx] = f2bf(s[tx][g]);
  }
}

// ---- GEMM1: encW[m][g] = sum_h enc[m][h] * Wt[g][h]  (A fp32 reg-staged+cvt)
__global__ __launch_bounds__(256) void gemm1_abt(
    const float* __restrict__ enc, const unsigned short* __restrict__ Wt,
    unsigned short* __restrict__ encW) {
  constexpr int K = 512, N = 512, BK = 32;
  __shared__ __align__(16) short As[128 * BK];
  __shared__ __align__(16) short Bs[128 * BK];

  const int g = blockIdx.x;
  const int work = (g & 7) * 64 + (g >> 3);      // bijective on [0,512)
  const int bxm = work >> 2, byn = work & 3;

  const int tid = threadIdx.x;
  const int wave = tid >> 6, lane = tid & 63;
  const int wm = wave >> 1, wn = wave & 1;
  const int r = lane & 15, q = lane >> 4;

  const float* Ab = enc + (long)bxm * 128 * K;
  const unsigned short* Bb = Wt + (long)byn * 128 * K;

  const int srow = tid >> 1, shalf = tid & 1;
  const float* arow = Ab + (long)srow * K + shalf * 16;

  f32x4 acc[4][4] = {};
  float4 av[4];
#pragma unroll
  for (int j = 0; j < 4; ++j) av[j] = ((const float4*)arow)[j];

  for (int kt = 0; kt < K; kt += BK) {
    ushort8 o0, o1;
    o0[0] = f2bf(av[0].x); o0[1] = f2bf(av[0].y); o0[2] = f2bf(av[0].z); o0[3] = f2bf(av[0].w);
    o0[4] = f2bf(av[1].x); o0[5] = f2bf(av[1].y); o0[6] = f2bf(av[1].z); o0[7] = f2bf(av[1].w);
    o1[0] = f2bf(av[2].x); o1[1] = f2bf(av[2].y); o1[2] = f2bf(av[2].z); o1[3] = f2bf(av[2].w);
    o1[4] = f2bf(av[3].x); o1[5] = f2bf(av[3].y); o1[6] = f2bf(av[3].z); o1[7] = f2bf(av[3].w);
    *(ushort8*)&As[srow * BK + shalf * 16 + 0] = o0;
    *(ushort8*)&As[srow * BK + shalf * 16 + 8] = o1;

#pragma unroll
    for (int j = 0; j < 2; ++j) {
      int c = (j * 4 + wave) * 64 + lane;
      int row = c >> 2;
      int coff = (c & 3) * 8;
      __builtin_amdgcn_global_load_lds(
          (const __attribute__((address_space(1))) void*)(Bb + (long)row * K + kt + coff),
          (__attribute__((address_space(3))) void*)(Bs + (j * 4 + wave) * 512),
          16, 0, 0);
    }
    __syncthreads();

    short8 af[4], bfr[4];
#pragma unroll
    for (int m = 0; m < 4; ++m)
      af[m] = *(const short8*)&As[(wm * 64 + m * 16 + r) * BK + q * 8];
#pragma unroll
    for (int n = 0; n < 4; ++n)
      bfr[n] = *(const short8*)&Bs[(wn * 64 + n * 16 + r) * BK + q * 8];

    if (kt + BK < K) {
      const float* ap = arow + kt + BK;
#pragma unroll
      for (int j = 0; j < 4; ++j) av[j] = ((const float4*)ap)[j];
    }

#pragma unroll
    for (int m = 0; m < 4; ++m)
#pragma unroll
      for (int n = 0; n < 4; ++n)
        acc[m][n] = __builtin_amdgcn_mfma_f32_16x16x32_bf16(af[m], bfr[n], acc[m][n], 0, 0, 0);
    __syncthreads();
  }

  const long rowbase = (long)bxm * 128 + wm * 64;
  const long colbase = (long)byn * 128 + wn * 64;
#pragma unroll
  for (int m = 0; m < 4; ++m)
#pragma unroll
    for (int n = 0; n < 4; ++n)
#pragma unroll
      for (int j = 0; j < 4; ++j) {
        long row = rowbase + m * 16 + q * 4 + j;
        long col = colbase + n * 16 + r;
        encW[row * (long)N + col] = f2bf(acc[m][n][j]);
      }
}

// ---------------- GEMM2: 256x256 8-phase, A read directly from fp32 dec ------
// scores[b][d][e] = sum_g dec[b,d,g] * encW[b,e,g] + bias
// B (encW, bf16): gload_lds with pre-swizzled source.
// A (dec, fp32): reg-staged async — global_load_dwordx4 x4 issued ~2 phases
// early, f2bf cvt + swizzled ds_write_b128 x2 after the VMCNT retiring them.
// Per-tile FIFO: A0[4] B0[2] A1[4] B1[2]; waits VMCNT(6)/VMCNT(6)/VMCNT(2).

#define VMCNT(n) asm volatile("s_waitcnt vmcnt(" #n ")" ::: "memory")
#define LGKM0 asm volatile("s_waitcnt lgkmcnt(0)" ::: "memory")
#define BARRIER __builtin_amdgcn_s_barrier()

#define BSTAGE(LBASE, tt, kkv)                                                \
  do {                                                                        \
    _Pragma("unroll") for (int j_ = 0; j_ < 2; ++j_) {                        \
      int c_ = w * 2 + j_;                                                    \
      __builtin_amdgcn_global_load_lds(                                       \
          (const __attribute__((address_space(1))) void*)(                    \
              Bb + ((long)(c_ * 16 + srow)) * 512 + (tt) * 64 + (kkv) * 32 + scol), \
          (__attribute__((address_space(3))) void*)((LBASE) + (c_ << 10)),    \
          16, 0, 0);                                                          \
    }                                                                         \
  } while (0)

#define ALOAD(r0, r1, r2, r3, tt, kkv)                                        \
  do {                                                                        \
    const float* p_ = asrc + (tt) * 64 + (kkv) * 32;                          \
    r0 = *(const float4*)(p_);                                                \
    r1 = *(const float4*)(p_ + 4);                                            \
    r2 = *(const float4*)(p_ + 8192);                                         \
    r3 = *(const float4*)(p_ + 8196);                                         \
  } while (0)

#define ACVT(LBASE, kkv, r0, r1, r2, r3)                                      \
  do {                                                                        \
    ushort8 o0_, o1_;                                                         \
    o0_[0] = f2bf(r0.x); o0_[1] = f2bf(r0.y); o0_[2] = f2bf(r0.z); o0_[3] = f2bf(r0.w); \
    o0_[4] = f2bf(r1.x); o0_[5] = f2bf(r1.y); o0_[6] = f2bf(r1.z); o0_[7] = f2bf(r1.w); \
    o1_[0] = f2bf(r2.x); o1_[1] = f2bf(r2.y); o1_[2] = f2bf(r2.z); o1_[3] = f2bf(r2.w); \
    o1_[4] = f2bf(r3.x); o1_[5] = f2bf(r3.y); o1_[6] = f2bf(r3.z); o1_[7] = f2bf(r3.w); \
    *(ushort8*)((LBASE) + (kkv) * 16384 + awoff) = o0_;                       \
    *(ushort8*)((LBASE) + (kkv) * 16384 + awoff + 1024) = o1_;                \
  } while (0)

#define LOADFRAG_B(Bc, kkv)                                                   \
  _Pragma("unroll") for (int n_ = 0; n_ < 4; ++n_)                            \
    bf[kkv][n_] = *(const short8*)((Bc) + (kkv) * 16384 + ((wn * 4 + n_) << 10) + lconst)

#define LOADFRAG_A(Ac, kkv, mb)                                               \
  _Pragma("unroll") for (int i_ = 0; i_ < 4; ++i_)                            \
    af[i_] = *(const short8*)((Ac) + (kkv) * 16384 + ((wm * 8 + (mb) + i_) << 10) + lconst)

#define COMPUTE(kkv, mb)                                                      \
  do {                                                                        \
    BARRIER;                                                                  \
    LGKM0;                                                                    \
    __builtin_amdgcn_sched_barrier(0);                                        \
    __builtin_amdgcn_s_setprio(1);                                            \
    _Pragma("unroll") for (int i_ = 0; i_ < 4; ++i_)                          \
      _Pragma("unroll") for (int n_ = 0; n_ < 4; ++n_)                        \
        acc[(mb) + i_][n_] = __builtin_amdgcn_mfma_f32_16x16x32_bf16(         \
            af[i_], bf[kkv][n_], acc[(mb) + i_][n_], 0, 0, 0);                \
    __builtin_amdgcn_s_setprio(0);                                            \
  } while (0)

__global__ __launch_bounds__(512, 2) void gemm2_8ph(
    const float* __restrict__ dec,          // [8*2048][512] fp32
    const unsigned short* __restrict__ Bt,  // encW [8*2048][512] bf16
    float* __restrict__ C, const float* __restrict__ bias) {
  __shared__ __align__(16) char Lds[131072];
#define LDS_A(d) (Lds + (d) * 32768)
#define LDS_B(d) (Lds + 65536 + (d) * 32768)

  int flat = blockIdx.x;
  int sw = (flat & 7) * 64 + (flat >> 3);
  int z = sw >> 6, xy = sw & 63, bx = xy & 7, by = xy >> 3;

  const int tid = threadIdx.x;
  const int w = tid >> 6, lane = tid & 63;
  const int wm = w >> 2, wn = w & 3;
  const int base_r = lane & 15, q = lane >> 4;
  const int lconst = base_r * 64 + ((q * 16) ^ ((base_r & 8) << 2));
  const int srow = lane >> 2;
  const int scol = ((lane & 3) * 8) ^ (((lane >> 5) & 1) << 4);

  // A-staging source: row = bx*256 + w*32 + (lane>>2) (+16 for second half),
  // col = (lane&3)*8 ^ ((lane>>5)<<4) — pre-swizzled so LDS content is
  // byte-identical to the gload_lds linear-dest layout.
  const float* asrc = dec + ((long)z * 2048 + bx * 256 + w * 32 + (lane >> 2)) * 512 +
                      (((lane & 3) * 8) ^ ((lane >> 5) << 4));
  const int awoff = w * 2048 + lane * 16;   // swizzled ds_write dest (bytes)

  const unsigned short* Bb = Bt + ((long)z * 2048 + by * 256) * 512;

  f32x4 acc[8][4] = {};
  short8 af[4];
  short8 bf[2][4];
  float4 a00, a01, a02, a03;   // k-half 0 in flight
  float4 a10, a11, a12, a13;   // k-half 1 in flight

  // prologue: FIFO A0[4] B0[2] A1[4] B1[2]
  ALOAD(a00, a01, a02, a03, 0, 0);
  BSTAGE(LDS_B(0), 0, 0);
  ALOAD(a10, a11, a12, a13, 0, 1);
  BSTAGE(LDS_B(0) + 16384, 0, 1);
  VMCNT(6);                 // A0 + B0 retired
  ACVT(LDS_A(0), 0, a00, a01, a02, a03);
  VMCNT(2);                 // A1 retired (B1 may remain)
  ACVT(LDS_A(0), 1, a10, a11, a12, a13);
  LGKM0;
  BARRIER;

  for (int t = 0; t < 7; ++t) {
    const char* Ac = LDS_A(t & 1);
    const char* Bc = LDS_B(t & 1);
    char* An = LDS_A((t + 1) & 1);
    char* Bn = LDS_B((t + 1) & 1);
    // ph1: issue A(t+1,k0)
    LOADFRAG_B(Bc, 0);
    LOADFRAG_A(Ac, 0, 0);
    ALOAD(a00, a01, a02, a03, t + 1, 0);
    COMPUTE(0, 0);
    BARRIER;
    // ph2: stage B(t+1,k0); retire B(t,k1) leftovers
    LOADFRAG_A(Ac, 0, 4);
    BSTAGE(Bn, t + 1, 0);
    COMPUTE(0, 4);
    VMCNT(6);
    BARRIER;
    // ph3: issue A(t+1,k1); cvt+write A(t+1,k0)
    LOADFRAG_B(Bc, 1);
    LOADFRAG_A(Ac, 1, 0);
    ALOAD(a10, a11, a12, a13, t + 1, 1);
    COMPUTE(1, 0);
    VMCNT(6);               // A(t+1,k0) retired
    ACVT(An, 0, a00, a01, a02, a03);
    LGKM0;
    BARRIER;
    // ph4: stage B(t+1,k1); cvt+write A(t+1,k1)
    LOADFRAG_A(Ac, 1, 4);
    BSTAGE(Bn + 16384, t + 1, 1);
    COMPUTE(1, 4);
    VMCNT(2);
    ACVT(An, 1, a10, a11, a12, a13);
    LGKM0;
    BARRIER;
  }
  // tail tile 7 (parity 1), no staging
  {
    const char* Ac = LDS_A(1);
    const char* Bc = LDS_B(1);
    LOADFRAG_B(Bc, 0);
    LOADFRAG_A(Ac, 0, 0);
    COMPUTE(0, 0);
    BARRIER;
    LOADFRAG_A(Ac, 0, 4);
    COMPUTE(0, 4);
    VMCNT(0);               // retire B(7,k1) before its frag reads
    BARRIER;
    LOADFRAG_B(Bc, 1);
    LOADFRAG_A(Ac, 1, 0);
    COMPUTE(1, 0);
    BARRIER;
    LOADFRAG_A(Ac, 1, 4);
    COMPUTE(1, 4);
    BARRIER;
  }

  const float bv = bias[0];
  float* Cb = C + ((long)z * 2048 + bx * 256 + wm * 128) * 2048 + by * 256 + wn * 64;
#pragma unroll
  for (int m = 0; m < 8; ++m)
#pragma unroll
    for (int n = 0; n < 4; ++n)
#pragma unroll
      for (int j = 0; j < 4; ++j)
        Cb[(long)(m * 16 + q * 4 + j) * 2048 + n * 16 + base_r] = acc[m][n][j] + bv;
#undef LDS_A
#undef LDS_B
}

extern "C" void kernel_launch(void* const* d_in, const int* in_sizes, int n_in,
                              void* d_out, int out_size, void* d_ws, size_t ws_size,
                              hipStream_t stream) {
  const float* enc  = (const float*)d_in[0];  // [8,2048,512]
  const float* dec  = (const float*)d_in[1];  // [8,2048,512]
  const float* W    = (const float*)d_in[2];  // [1,512,512]
  const float* bias = (const float*)d_in[3];  // [1]
  float* out = (float*)d_out;                 // [8,2048,2048] fp32

  constexpr int H = 512;

  unsigned short* Wt   = (unsigned short*)d_ws;          // 0.5 MB
  unsigned short* encW = Wt + (long)H * H;               // 16.8 MB

  wt_kernel<<<dim3(8, 8), 256, 0, stream>>>(W, Wt);

  gemm1_abt<<<dim3(512, 1, 1), 256, 0, stream>>>(enc, Wt, encW);

  gemm2_8ph<<<dim3(512, 1, 1), 512, 0, stream>>>(dec, encW, out, bias);
}

// Round 6
// 81.467 us; speedup vs baseline: 1.1058x; 1.1058x over previous
//
#include <hip/hip_runtime.h>

typedef __attribute__((ext_vector_type(8))) short short8;
typedef __attribute__((ext_vector_type(4))) float f32x4;
typedef __attribute__((ext_vector_type(8))) unsigned short ushort8;

__device__ __forceinline__ unsigned short f2bf(float x) {
  union { float f; unsigned u; } v; v.f = x;
  unsigned r = v.u + 0x7fffu + ((v.u >> 16) & 1u);   // round-to-nearest-even
  return (unsigned short)(r >> 16);
}

// ---------------- W[h][g] -> Wt[g][h] transpose + convert (512x512) ----------
__global__ __launch_bounds__(256) void wt_kernel(
    const float* __restrict__ W, unsigned short* __restrict__ Wt) {
  __shared__ float s[64][65];
  int g0 = blockIdx.x * 64, h0 = blockIdx.y * 64;
  int tx = threadIdx.x & 63, ty = threadIdx.x >> 6;
#pragma unroll
  for (int rr = 0; rr < 16; ++rr) {
    int h = ty * 16 + rr;
    s[h][tx] = W[(long)(h0 + h) * 512 + g0 + tx];
  }
  __syncthreads();
#pragma unroll
  for (int rr = 0; rr < 16; ++rr) {
    int g = ty * 16 + rr;
    Wt[(long)(g0 + g) * 512 + h0 + tx] = f2bf(s[tx][g]);
  }
}

// ---- Fused: gemm1 (blocks 0..511) + dec fp32->bf16 convert (blocks 512..4607)
__global__ __launch_bounds__(256) void gemm1_plus_cvtdec(
    const float* __restrict__ enc, const unsigned short* __restrict__ Wt,
    unsigned short* __restrict__ encW,
    const float* __restrict__ dec, unsigned short* __restrict__ dec_bf) {
  if (blockIdx.x >= 512) {
    int i = (blockIdx.x - 512) * 256 + threadIdx.x;
    const float4* p = (const float4*)(dec + (long)i * 8);
    float4 a = p[0], b = p[1];
    ushort8 o;
    o[0] = f2bf(a.x); o[1] = f2bf(a.y); o[2] = f2bf(a.z); o[3] = f2bf(a.w);
    o[4] = f2bf(b.x); o[5] = f2bf(b.y); o[6] = f2bf(b.z); o[7] = f2bf(b.w);
    *(ushort8*)(dec_bf + (long)i * 8) = o;
    return;
  }

  constexpr int K = 512, N = 512, BK = 32;
  __shared__ __align__(16) short As[128 * BK];
  __shared__ __align__(16) short Bs[128 * BK];

  const int g = blockIdx.x;
  const int work = (g & 7) * 64 + (g >> 3);      // bijective on [0,512)
  const int bxm = work >> 2, byn = work & 3;

  const int tid = threadIdx.x;
  const int wave = tid >> 6, lane = tid & 63;
  const int wm = wave >> 1, wn = wave & 1;
  const int r = lane & 15, q = lane >> 4;

  const float* Ab = enc + (long)bxm * 128 * K;
  const unsigned short* Bb = Wt + (long)byn * 128 * K;

  const int srow = tid >> 1, shalf = tid & 1;
  const float* arow = Ab + (long)srow * K + shalf * 16;

  f32x4 acc[4][4] = {};
  float4 av[4];
#pragma unroll
  for (int j = 0; j < 4; ++j) av[j] = ((const float4*)arow)[j];

  for (int kt = 0; kt < K; kt += BK) {
    ushort8 o0, o1;
    o0[0] = f2bf(av[0].x); o0[1] = f2bf(av[0].y); o0[2] = f2bf(av[0].z); o0[3] = f2bf(av[0].w);
    o0[4] = f2bf(av[1].x); o0[5] = f2bf(av[1].y); o0[6] = f2bf(av[1].z); o0[7] = f2bf(av[1].w);
    o1[0] = f2bf(av[2].x); o1[1] = f2bf(av[2].y); o1[2] = f2bf(av[2].z); o1[3] = f2bf(av[2].w);
    o1[4] = f2bf(av[3].x); o1[5] = f2bf(av[3].y); o1[6] = f2bf(av[3].z); o1[7] = f2bf(av[3].w);
    *(ushort8*)&As[srow * BK + shalf * 16 + 0] = o0;
    *(ushort8*)&As[srow * BK + shalf * 16 + 8] = o1;

#pragma unroll
    for (int j = 0; j < 2; ++j) {
      int c = (j * 4 + wave) * 64 + lane;
      int row = c >> 2;
      int coff = (c & 3) * 8;
      __builtin_amdgcn_global_load_lds(
          (const __attribute__((address_space(1))) void*)(Bb + (long)row * K + kt + coff),
          (__attribute__((address_space(3))) void*)(Bs + (j * 4 + wave) * 512),
          16, 0, 0);
    }
    __syncthreads();

    short8 af[4], bfr[4];
#pragma unroll
    for (int m = 0; m < 4; ++m)
      af[m] = *(const short8*)&As[(wm * 64 + m * 16 + r) * BK + q * 8];
#pragma unroll
    for (int n = 0; n < 4; ++n)
      bfr[n] = *(const short8*)&Bs[(wn * 64 + n * 16 + r) * BK + q * 8];

    if (kt + BK < K) {
      const float* ap = arow + kt + BK;
#pragma unroll
      for (int j = 0; j < 4; ++j) av[j] = ((const float4*)ap)[j];
    }

#pragma unroll
    for (int m = 0; m < 4; ++m)
#pragma unroll
      for (int n = 0; n < 4; ++n)
        acc[m][n] = __builtin_amdgcn_mfma_f32_16x16x32_bf16(af[m], bfr[n], acc[m][n], 0, 0, 0);
    __syncthreads();
  }

  const long rowbase = (long)bxm * 128 + wm * 64;
  const long colbase = (long)byn * 128 + wn * 64;
#pragma unroll
  for (int m = 0; m < 4; ++m)
#pragma unroll
    for (int n = 0; n < 4; ++n)
#pragma unroll
      for (int j = 0; j < 4; ++j) {
        long row = rowbase + m * 16 + q * 4 + j;
        long col = colbase + n * 16 + r;
        encW[row * (long)N + col] = f2bf(acc[m][n][j]);
      }
}

// ---------------- GEMM2: 128x128 tiles, 4 waves, 64KB LDS -> 2 blocks/CU -----
// scores[b][d][e] = sum_g dec_bf[b,d,g] * encW[b,e,g] + bias
// BK=64 (2 k-halves of 32). 8-phase-per-2-halves schedule with counted VMCNT(4).
// Two independent blocks per CU overlap each other's barrier/vmcnt stalls.

#define VMCNT(n) asm volatile("s_waitcnt vmcnt(" #n ")" ::: "memory")
#define LGKM0 asm volatile("s_waitcnt lgkmcnt(0)" ::: "memory")
#define BARRIER __builtin_amdgcn_s_barrier()

// stage one 8KB k-half (8 chunks of 1KB): 2 gload_lds ops/thread
#define STAGE2(GP, LBASE, tt, kkv)                                            \
  do {                                                                        \
    _Pragma("unroll") for (int j_ = 0; j_ < 2; ++j_) {                        \
      int c_ = w * 2 + j_;                                                    \
      __builtin_amdgcn_global_load_lds(                                       \
          (const __attribute__((address_space(1))) void*)(                    \
              (GP) + ((long)(c_ * 16 + srow)) * 512 + (tt) * 64 + (kkv) * 32 + scol), \
          (__attribute__((address_space(3))) void*)((LBASE) + (kkv) * 8192 + (c_ << 10)), \
          16, 0, 0);                                                          \
    }                                                                         \
  } while (0)

#define LOADFRAG_B2(Bc, kkv)                                                  \
  _Pragma("unroll") for (int n_ = 0; n_ < 4; ++n_)                            \
    bf[n_] = *(const short8*)((Bc) + (kkv) * 8192 + ((wn * 4 + n_) << 10) + lconst)

#define LOADFRAG_A2(Ac, kkv, mh)                                              \
  _Pragma("unroll") for (int i_ = 0; i_ < 2; ++i_)                            \
    af[i_] = *(const short8*)((Ac) + (kkv) * 8192 + ((wm * 4 + (mh) * 2 + i_) << 10) + lconst)

#define COMPUTE2(mh)                                                          \
  do {                                                                        \
    BARRIER;                                                                  \
    LGKM0;                                                                    \
    __builtin_amdgcn_sched_barrier(0);                                        \
    __builtin_amdgcn_s_setprio(1);                                            \
    _Pragma("unroll") for (int i_ = 0; i_ < 2; ++i_)                          \
      _Pragma("unroll") for (int n_ = 0; n_ < 4; ++n_)                        \
        acc[(mh) * 2 + i_][n_] = __builtin_amdgcn_mfma_f32_16x16x32_bf16(     \
            af[i_], bf[n_], acc[(mh) * 2 + i_][n_], 0, 0, 0);                 \
    __builtin_amdgcn_s_setprio(0);                                            \
  } while (0)

__global__ __launch_bounds__(256, 2) void gemm2_128(
    const unsigned short* __restrict__ A,   // dec_bf [8*2048][512]
    const unsigned short* __restrict__ Bt,  // encW   [8*2048][512]
    float* __restrict__ C, const float* __restrict__ bias) {
  __shared__ __align__(16) char Lds[65536];
#define LDS_A(d) (Lds + (d) * 16384)
#define LDS_B(d) (Lds + 32768 + (d) * 16384)

  // XCD swizzle: 2048 blocks, 256/XCD -> one batch per XCD; by fastest
  int flat = blockIdx.x;
  int sw = (flat & 7) * 256 + (flat >> 3);
  int z = sw >> 8, bx = (sw >> 4) & 15, by = sw & 15;

  const int tid = threadIdx.x;
  const int w = tid >> 6, lane = tid & 63;
  const int wm = w >> 1, wn = w & 1;            // 2x2 waves, 64x64 out each
  const int base_r = lane & 15, q = lane >> 4;
  const int lconst = base_r * 64 + ((q * 16) ^ ((base_r & 8) << 2));
  const int srow = lane >> 2;
  const int scol = ((lane & 3) * 8) ^ (((lane >> 5) & 1) << 4);

  const unsigned short* Ab = A + ((long)z * 2048 + bx * 128) * 512;
  const unsigned short* Bb = Bt + ((long)z * 2048 + by * 128) * 512;

  f32x4 acc[4][4] = {};
  short8 af[2];
  short8 bf[4];

  // prologue: FIFO A0(0)[2] B0(0)[2] A1(0)[2] B1(0)[2]
  STAGE2(Ab, LDS_A(0), 0, 0);
  STAGE2(Bb, LDS_B(0), 0, 0);
  STAGE2(Ab, LDS_A(0), 0, 1);
  STAGE2(Bb, LDS_B(0), 0, 1);
  VMCNT(4);                 // A0,B0 retired
  BARRIER;

  for (int t = 0; t < 7; ++t) {
    const char* Ac = LDS_A(t & 1);
    const char* Bc = LDS_B(t & 1);
    char* An = LDS_A((t + 1) & 1);
    char* Bn = LDS_B((t + 1) & 1);
    // ph1: kk0, m0-1; stage A(t+1,k0)
    LOADFRAG_B2(Bc, 0);
    LOADFRAG_A2(Ac, 0, 0);
    STAGE2(Ab, An, t + 1, 0);
    COMPUTE2(0);
    BARRIER;
    // ph2: kk0, m2-3; stage B(t+1,k0); retire A1(t),B1(t)
    LOADFRAG_A2(Ac, 0, 1);
    STAGE2(Bb, Bn, t + 1, 0);
    COMPUTE2(1);
    VMCNT(4);
    BARRIER;
    // ph3: kk1, m0-1; stage A(t+1,k1)
    LOADFRAG_B2(Bc, 1);
    LOADFRAG_A2(Ac, 1, 0);
    STAGE2(Ab, An, t + 1, 1);
    COMPUTE2(0);
    BARRIER;
    // ph4: kk1, m2-3; stage B(t+1,k1); retire A0(t+1),B0(t+1)
    LOADFRAG_A2(Ac, 1, 1);
    STAGE2(Bb, Bn, t + 1, 1);
    COMPUTE2(1);
    VMCNT(4);
    BARRIER;
  }
  // tail tile 7 (parity 1), no staging
  {
    const char* Ac = LDS_A(1);
    const char* Bc = LDS_B(1);
    LOADFRAG_B2(Bc, 0);
    LOADFRAG_A2(Ac, 0, 0);
    COMPUTE2(0);
    BARRIER;
    LOADFRAG_A2(Ac, 0, 1);
    COMPUTE2(1);
    VMCNT(0);               // drain A1(7),B1(7)
    BARRIER;
    LOADFRAG_B2(Bc, 1);
    LOADFRAG_A2(Ac, 1, 0);
    COMPUTE2(0);
    BARRIER;
    LOADFRAG_A2(Ac, 1, 1);
    COMPUTE2(1);
  }

  const float bv = bias[0];
  float* Cb = C + ((long)z * 2048 + bx * 128 + wm * 64) * 2048 + by * 128 + wn * 64;
#pragma unroll
  for (int m = 0; m < 4; ++m)
#pragma unroll
    for (int n = 0; n < 4; ++n)
#pragma unroll
      for (int j = 0; j < 4; ++j)
        Cb[(long)(m * 16 + q * 4 + j) * 2048 + n * 16 + base_r] = acc[m][n][j] + bv;
#undef LDS_A
#undef LDS_B
}

extern "C" void kernel_launch(void* const* d_in, const int* in_sizes, int n_in,
                              void* d_out, int out_size, void* d_ws, size_t ws_size,
                              hipStream_t stream) {
  const float* enc  = (const float*)d_in[0];  // [8,2048,512]
  const float* dec  = (const float*)d_in[1];  // [8,2048,512]
  const float* W    = (const float*)d_in[2];  // [1,512,512]
  const float* bias = (const float*)d_in[3];  // [1]
  float* out = (float*)d_out;                 // [8,2048,2048] fp32

  constexpr int Bn = 8, S = 2048, H = 512;
  constexpr long NE = (long)Bn * S * H;       // 8388608

  unsigned short* dec_bf = (unsigned short*)d_ws;        // 16.8 MB
  unsigned short* Wt     = dec_bf + NE;                  // 0.5 MB
  unsigned short* encW   = Wt + (long)H * H;             // 16.8 MB

  wt_kernel<<<dim3(8, 8), 256, 0, stream>>>(W, Wt);

  // gemm1 (512 blocks) + dec conversion (4096 blocks) in one launch
  gemm1_plus_cvtdec<<<dim3(512 + 4096, 1, 1), 256, 0, stream>>>(
      enc, Wt, encW, dec, dec_bf);

  // scores[b][d][e] = dec[b,d,:] . encW[b,e,:] + bias
  gemm2_128<<<dim3(2048, 1, 1), 256, 0, stream>>>(dec_bf, encW, out, bias);
}